// Round 17
// baseline (417.246 us; speedup 1.0000x reference)
//
#include <hip/hip_runtime.h>
#include <hip/hip_bf16.h>

#define BB 16
#define CC 64
#define NN 2048
#define TT 24
#define JJ (CC*TT)      /* 1536 */
#define NT (NN*TT)

typedef unsigned short u16;
typedef unsigned int u32;
typedef __bf16 bf16x8 __attribute__((ext_vector_type(8)));
typedef u16 u16x8 __attribute__((ext_vector_type(8)));
typedef float f32x4 __attribute__((ext_vector_type(4)));
typedef u32 u32x4 __attribute__((ext_vector_type(4)));

static __device__ __forceinline__ u16 f2bf(float f) {
  union { float f; u32 u; } v; v.f = f;
  u32 u = v.u;
  u += 0x7fffu + ((u >> 16) & 1u);
  return (u16)(u >> 16);
}
static __device__ __forceinline__ float bf2f(u16 h) {
  union { u32 u; float f; } v; v.u = ((u32)h) << 16; return v.f;
}
static __device__ __forceinline__ bf16x8 ld_bf8(const u16* p) {
  return __builtin_bit_cast(bf16x8, *(const u16x8*)p);
}
#define MFMA16(a,b,c) __builtin_amdgcn_mfma_f32_16x16x32_bf16((a),(b),(c),0,0,0)

static __device__ __forceinline__ void gload16(const u16* g, u16* lds) {
  __builtin_amdgcn_global_load_lds(
      (const __attribute__((address_space(1))) u32*)g,
      (__attribute__((address_space(3))) u32*)lds, 16, 0, 0);
}

// ============ kA: fused channel-reduce (k partials) + bf16 transpose =======
__global__ __launch_bounds__(256) void kA(
    const float* __restrict__ x, const float* __restrict__ alpha,
    u16* __restrict__ xT, float* __restrict__ kpart) {
  int bid = blockIdx.x;
  int b  = bid >> 5;
  int mt = (bid >> 1) & 15;
  int ch = bid & 1;
  int m0 = mt * 128;
  int tid = threadIdx.x;
  __shared__ float tile[128][25];
  float kacc[12];
  #pragma unroll
  for (int e = 0; e < 12; ++e) kacc[e] = 0.f;

  for (int c = ch*32; c < ch*32 + 32; ++c) {
    const float4* src4 = (const float4*)(x + ((size_t)(b*CC + c)*NN + m0)*TT);
    float a = alpha[c];
    float4 v[3];
    #pragma unroll
    for (int q = 0; q < 3; ++q) v[q] = src4[tid*3 + q];
    __syncthreads();
    #pragma unroll
    for (int q = 0; q < 3; ++q) {
      int idx = tid*3 + q;
      int mm = idx / 6, off = (idx - mm*6)*4;
      tile[mm][off]   = v[q].x; tile[mm][off+1] = v[q].y;
      tile[mm][off+2] = v[q].z; tile[mm][off+3] = v[q].w;
      kacc[q*4+0] += a*v[q].x; kacc[q*4+1] += a*v[q].y;
      kacc[q*4+2] += a*v[q].z; kacc[q*4+3] += a*v[q].w;
    }
    __syncthreads();
    #pragma unroll
    for (int qq = 0; qq < 6; ++qq) {
      int idx = tid*6 + qq;
      int t = idx >> 6, mp = idx & 63;
      u32 lo = f2bf(tile[2*mp][t]);
      u32 hi = f2bf(tile[2*mp+1][t]);
      ((u32*)(xT + ((size_t)((b*CC + c)*TT + t))*NN + m0))[mp] = lo | (hi << 16);
    }
  }
  float* kp = kpart + (size_t)ch*BB*NT + (size_t)b*NT + (size_t)m0*TT + tid*12;
  #pragma unroll
  for (int q = 0; q < 3; ++q)
    *(float4*)(kp + q*4) = make_float4(kacc[q*4], kacc[q*4+1], kacc[q*4+2], kacc[q*4+3]);
}

// ------- K2': kG = k@Gw; emit hi/lo bf16 splits of kG and k (K=32 pad) -----
__global__ __launch_bounds__(256) void k2_prep(
    const float* __restrict__ kpart, const float* __restrict__ Gw,
    u16* __restrict__ kGhi, u16* __restrict__ kGlo,
    u16* __restrict__ kPhi, u16* __restrict__ kPlo) {
  __shared__ float gw[TT*TT];
  for (int i = threadIdx.x; i < TT*TT; i += 256) gw[i] = Gw[i];
  __syncthreads();
  int row = blockIdx.x * blockDim.x + threadIdx.x;
  if (row >= BB*NN) return;
  float kr[TT];
  const float4* s0 = (const float4*)(kpart + (size_t)row*TT);
  const float4* s1 = (const float4*)(kpart + (size_t)BB*NT + (size_t)row*TT);
  #pragma unroll
  for (int q = 0; q < 6; ++q) {
    float4 a = s0[q], bv = s1[q];
    kr[4*q]   = a.x + bv.x; kr[4*q+1] = a.y + bv.y;
    kr[4*q+2] = a.z + bv.z; kr[4*q+3] = a.w + bv.w;
  }
  float o[TT];
  #pragma unroll
  for (int s = 0; s < TT; ++s) o[s] = 0.f;
  #pragma unroll
  for (int t = 0; t < TT; ++t) {
    float kv = kr[t];
    #pragma unroll
    for (int s = 0; s < TT; ++s) o[s] += kv * gw[t*TT + s];
  }
  size_t rb = (size_t)row * 32;
  u32* ghi = (u32*)(kGhi + rb); u32* glo = (u32*)(kGlo + rb);
  u32* phi = (u32*)(kPhi + rb); u32* plo = (u32*)(kPlo + rb);
  #pragma unroll
  for (int sp = 0; sp < 16; ++sp) {
    float v0 = (2*sp   < TT) ? o[2*sp]   : 0.f;
    float v1 = (2*sp+1 < TT) ? o[2*sp+1] : 0.f;
    u16 h0 = f2bf(v0), h1 = f2bf(v1);
    u16 l0 = f2bf(v0 - bf2f(h0)), l1 = f2bf(v1 - bf2f(h1));
    ghi[sp] = (u32)h0 | ((u32)h1 << 16);
    glo[sp] = (u32)l0 | ((u32)l1 << 16);
    float w0 = (2*sp   < TT) ? kr[2*sp]   : 0.f;
    float w1 = (2*sp+1 < TT) ? kr[2*sp+1] : 0.f;
    u16 ph0 = f2bf(w0), ph1 = f2bf(w1);
    u16 pl0 = f2bf(w0 - bf2f(ph0)), pl1 = f2bf(w1 - bf2f(ph1));
    phi[sp] = (u32)ph0 | ((u32)ph1 << 16);
    plo[sp] = (u32)pl0 | ((u32)pl1 << 16);
  }
}

// ---------- kW: W[b,n,m] bf16 = exp(s)*adj ; Zpart[b,n,mt] = sum exp(s) ----
__global__ __launch_bounds__(256) void kW(
    const u16* __restrict__ kGhi, const u16* __restrict__ kGlo,
    const u16* __restrict__ kPhi, const u16* __restrict__ kPlo,
    const float* __restrict__ adj, u16* __restrict__ Wm,
    float* __restrict__ Zpart) {
  int bid = blockIdx.x;
  int b = bid >> 8, nt = (bid >> 4) & 15, mt = bid & 15;
  int tid = threadIdx.x;
  int w = tid >> 6, l = tid & 63;
  __shared__ u16 wlds[128][128];
  size_t kgb = ((size_t)b*NN + nt*128) * 32;
  bf16x8 ahi[2], alo[2];
  #pragma unroll
  for (int nf = 0; nf < 2; ++nf) {
    size_t off = kgb + (size_t)(w*32 + nf*16 + (l & 15))*32 + (l >> 4)*8;
    ahi[nf] = ld_bf8(kGhi + off);
    alo[nf] = ld_bf8(kGlo + off);
  }
  f32x4 acc[2][8];
  #pragma unroll
  for (int mf = 0; mf < 8; ++mf) {
    size_t off = ((size_t)b*NN + mt*128 + mf*16 + (l & 15))*32 + (l >> 4)*8;
    bf16x8 bhi = ld_bf8(kPhi + off);
    bf16x8 blo = ld_bf8(kPlo + off);
    #pragma unroll
    for (int nf = 0; nf < 2; ++nf) {
      f32x4 a = {0.f, 0.f, 0.f, 0.f};
      a = MFMA16(ahi[nf], blo, a);
      a = MFMA16(alo[nf], bhi, a);
      a = MFMA16(ahi[nf], bhi, a);
      acc[nf][mf] = a;
    }
  }
  #pragma unroll
  for (int nf = 0; nf < 2; ++nf)
    #pragma unroll
    for (int r = 0; r < 4; ++r) {
      int nl = w*32 + nf*16 + (l >> 4)*4 + r;
      float rs = 0.f;
      #pragma unroll
      for (int mf = 0; mf < 8; ++mf) {
        int ml = mf*16 + (l & 15);
        float e = __expf(acc[nf][mf][r]);
        rs += e;
        float wv = e * adj[(size_t)(nt*128 + nl)*NN + mt*128 + ml];
        wlds[nl][ml] = f2bf(wv);
      }
      #pragma unroll
      for (int st = 1; st < 16; st <<= 1) rs += __shfl_xor(rs, st);
      if ((l & 15) == 0)
        Zpart[((size_t)b*NN + nt*128 + nl)*16 + mt] = rs;
    }
  __syncthreads();
  int row = tid >> 1, half = tid & 1;
  const u32x4* s4 = (const u32x4*)&wlds[row][half*64];
  u32x4* d4 = (u32x4*)(Wm + ((size_t)(b*NN + nt*128 + row))*NN + mt*128 + half*64);
  #pragma unroll
  for (int q = 0; q < 8; ++q) d4[q] = s4[q];
}

// ---------- k4: out = (W @ X)*rinv — 256x256, BK=64, ONE barrier per step --
// R9 structure (best of 7 measured k4 variants: ~272 us, MfmaUtil 32%,
// 0 bank conflicts). rinv computed in-prologue from Zpart (kZ folded in).
__global__ __launch_bounds__(512, 2) void k4_gemm(
    const u16* __restrict__ Wm, const u16* __restrict__ xT,
    const float* __restrict__ Zpart, float* __restrict__ out) {
  __shared__ __align__(16) u16 sA[2*256*64];   // [dbuf][256 rows][64]
  __shared__ __align__(16) u16 sB[2*256*64];
  __shared__ float rinv[256];

  int bid = blockIdx.x;
  int wg = (bid & 7) * 96 + (bid >> 3);        // bijective XCD chunking
  int b = wg / 48; int rem = wg - b*48;
  int nt = rem / 6, jt = rem - nt*6;

  int tid = threadIdx.x;
  int w = tid >> 6, l = tid & 63;
  int wr = w >> 2, wc = w & 3;
  int l15 = l & 15, l4 = l >> 4, lx = l & 7;

  // fragment read offsets (u16 units); row&7 == lx for both A and B rows
  int g0 = ((l4)     ^ lx) << 3;
  int g1 = ((4 + l4) ^ lx) << 3;
  int rbA = wr*8192 + l15*64;                  // A row = wr*128 + f*16 + l15
  int rbB = wc*4096 + l15*64;                  // B row = wc*64 + cf*16 + l15

  // staging: thread -> (row=tid>>3, slot=tid&7); src pre-inverse-swizzled
  int srow = tid >> 3, sslot = tid & 7;
  int sgx = (sslot ^ (srow & 7)) << 3;
  const size_t ROW64 = (size_t)64 * NN;
  const u16* pA = Wm + (size_t)b*NN*NN + (size_t)(nt*256 + srow)*NN + sgx;
  const u16* pB = xT + (size_t)b*JJ*NN + (size_t)(jt*256 + srow)*NN + sgx;
  int wbase = w << 9;   // wave-uniform LDS dest offset (lane adds 16B)

  f32x4 acc[8][4];
  #pragma unroll
  for (int f = 0; f < 8; ++f)
    #pragma unroll
    for (int cf = 0; cf < 4; ++cf) acc[f][cf] = (f32x4){0.f,0.f,0.f,0.f};

  // ---- prologue: rinv from Zpart (kZ folded) + stage tile 0, publish ----
  if (tid < 256) {
    const float4* zp = (const float4*)(Zpart + ((size_t)b*NN + nt*256 + tid)*16);
    float4 a = zp[0], bz = zp[1], c = zp[2], d = zp[3];
    float s = a.x+a.y+a.z+a.w + bz.x+bz.y+bz.z+bz.w
            + c.x+c.y+c.z+c.w + d.x+d.y+d.z+d.w;
    rinv[tid] = 1.f / s;
  }
  #pragma unroll
  for (int i = 0; i < 4; ++i) gload16(pA + (size_t)i*ROW64, sA + i*4096 + wbase);
  #pragma unroll
  for (int i = 0; i < 4; ++i) gload16(pB + (size_t)i*ROW64, sB + i*4096 + wbase);
  pA += 64; pB += 64;
  asm volatile("s_waitcnt vmcnt(0)" ::: "memory");
  __builtin_amdgcn_sched_barrier(0);
  __builtin_amdgcn_s_barrier();
  __builtin_amdgcn_sched_barrier(0);

  for (int kt = 0; kt < 32; ++kt) {
    int pb = (kt & 1) << 14;
    int qb = pb ^ 16384;
    // stage kt+1 into the other buffer (ungated; drains at end-of-step)
    if (kt < 31) {
      #pragma unroll
      for (int i = 0; i < 4; ++i) gload16(pA + (size_t)i*ROW64, sA + qb + i*4096 + wbase);
      #pragma unroll
      for (int i = 0; i < 4; ++i) gload16(pB + (size_t)i*ROW64, sB + qb + i*4096 + wbase);
      pA += 64; pB += 64;
    }
    __builtin_amdgcn_sched_barrier(0);

    bf16x8 a0[8], b0[4], a1[8], b1[4];
    // read order: b0(4), a0(8) | b1(4), a1(8)  — 24 ds_read_b128
    #pragma unroll
    for (int cf = 0; cf < 4; ++cf) b0[cf] = ld_bf8(sB + pb + rbB + cf*1024 + g0);
    #pragma unroll
    for (int f = 0; f < 8; ++f) a0[f] = ld_bf8(sA + pb + rbA + f*1024 + g0);
    __builtin_amdgcn_sched_barrier(0);                   // pin group boundary
    #pragma unroll
    for (int cf = 0; cf < 4; ++cf) b1[cf] = ld_bf8(sB + pb + rbB + cf*1024 + g1);
    #pragma unroll
    for (int f = 0; f < 8; ++f) a1[f] = ld_bf8(sA + pb + rbA + f*1024 + g1);

    // cluster 1: needs b0 + a0[0..3]  (first 9 of 24 reads; 4-bit field max 15)
    asm volatile("s_waitcnt lgkmcnt(15)" ::: "memory");
    __builtin_amdgcn_sched_barrier(0);
    __builtin_amdgcn_s_setprio(1);
    #pragma unroll
    for (int f = 0; f < 4; ++f)
      #pragma unroll
      for (int cf = 0; cf < 4; ++cf)
        acc[f][cf] = MFMA16(a0[f], b0[cf], acc[f][cf]);
    __builtin_amdgcn_s_setprio(0);
    // cluster 2: needs a0[4..7]  (first 12 reads)
    asm volatile("s_waitcnt lgkmcnt(12)" ::: "memory");
    __builtin_amdgcn_sched_barrier(0);
    __builtin_amdgcn_s_setprio(1);
    #pragma unroll
    for (int f = 4; f < 8; ++f)
      #pragma unroll
      for (int cf = 0; cf < 4; ++cf)
        acc[f][cf] = MFMA16(a0[f], b0[cf], acc[f][cf]);
    __builtin_amdgcn_s_setprio(0);
    // cluster 3: needs b1 + a1[0..3]  (first 20 reads)
    asm volatile("s_waitcnt lgkmcnt(4)" ::: "memory");
    __builtin_amdgcn_sched_barrier(0);
    __builtin_amdgcn_s_setprio(1);
    #pragma unroll
    for (int f = 0; f < 4; ++f)
      #pragma unroll
      for (int cf = 0; cf < 4; ++cf)
        acc[f][cf] = MFMA16(a1[f], b1[cf], acc[f][cf]);
    __builtin_amdgcn_s_setprio(0);
    // cluster 4: needs a1[4..7]  (all 24)
    asm volatile("s_waitcnt lgkmcnt(0)" ::: "memory");
    __builtin_amdgcn_sched_barrier(0);
    __builtin_amdgcn_s_setprio(1);
    #pragma unroll
    for (int f = 4; f < 8; ++f)
      #pragma unroll
      for (int cf = 0; cf < 4; ++cf)
        acc[f][cf] = MFMA16(a1[f], b1[cf], acc[f][cf]);
    __builtin_amdgcn_s_setprio(0);

    // end-of-step: drain own gloads (aged a full step), then single barrier
    asm volatile("s_waitcnt vmcnt(0)" ::: "memory");
    __builtin_amdgcn_sched_barrier(0);
    __builtin_amdgcn_s_barrier();
    __builtin_amdgcn_sched_barrier(0);
  }

  // ---- epilogue: normalize + store (rinv in LDS) ----
  int cj[4], tj4[4];
  #pragma unroll
  for (int cf = 0; cf < 4; ++cf) {
    int j = jt*256 + wc*64 + cf*16 + l15;
    cj[cf] = j / TT; tj4[cf] = j - cj[cf]*TT;
  }
  #pragma unroll
  for (int f = 0; f < 8; ++f)
    #pragma unroll
    for (int r = 0; r < 4; ++r) {
      int nl = wr*128 + f*16 + l4*4 + r;
      float rv = rinv[nl];
      #pragma unroll
      for (int cf = 0; cf < 4; ++cf)
        out[((size_t)(b*CC + cj[cf])*NN + nt*256 + nl)*TT + tj4[cf]] = acc[f][cf][r] * rv;
    }
}

extern "C" void kernel_launch(void* const* d_in, const int* in_sizes, int n_in,
                              void* d_out, int out_size, void* d_ws, size_t ws_size,
                              hipStream_t stream) {
  const float* x     = (const float*)d_in[0];
  const float* adj   = (const float*)d_in[1];
  const float* Gw    = (const float*)d_in[2];
  const float* alpha = (const float*)d_in[3];
  float* out = (float*)d_out;

  const size_t XT_B = (size_t)BB*JJ*NN*2;
  const size_t W_B  = (size_t)BB*NN*NN*2;
  const size_t KS_B = (size_t)BB*NN*32*2;
  char* base = (char*)d_ws;
  u16*   xT    = (u16*)base;
  u16*   Wm    = (u16*)(base + XT_B);
  float* kpart = (float*)(base + XT_B);            // overlay on Wm (dead then)
  u16*   kGhi  = (u16*)(base + XT_B + W_B);
  u16*   kGlo  = (u16*)(base + XT_B + W_B + KS_B);
  u16*   kPhi  = (u16*)(base + XT_B + W_B + 2*KS_B);
  u16*   kPlo  = (u16*)(base + XT_B + W_B + 3*KS_B);
  float* Zpart = (float*)(base + XT_B + W_B + 4*KS_B);

  kA<<<512, 256, 0, stream>>>(x, alpha, xT, kpart);
  k2_prep<<<BB*NN/256, 256, 0, stream>>>(kpart, Gw, kGhi, kGlo, kPhi, kPlo);
  kW<<<BB*16*16, 256, 0, stream>>>(kGhi, kGlo, kPhi, kPlo, adj, Wm, Zpart);
  k4_gemm<<<768, 512, 0, stream>>>(Wm, xT, Zpart, out);
}

// Round 18
// 409.514 us; speedup vs baseline: 1.0189x; 1.0189x over previous
//
#include <hip/hip_runtime.h>
#include <hip/hip_bf16.h>

#define BB 16
#define CC 64
#define NN 2048
#define TT 24
#define JJ (CC*TT)      /* 1536 */
#define NT (NN*TT)

typedef unsigned short u16;
typedef unsigned int u32;
typedef __bf16 bf16x8 __attribute__((ext_vector_type(8)));
typedef u16 u16x8 __attribute__((ext_vector_type(8)));
typedef float f32x4 __attribute__((ext_vector_type(4)));
typedef u32 u32x4 __attribute__((ext_vector_type(4)));

static __device__ __forceinline__ u16 f2bf(float f) {
  union { float f; u32 u; } v; v.f = f;
  u32 u = v.u;
  u += 0x7fffu + ((u >> 16) & 1u);
  return (u16)(u >> 16);
}
static __device__ __forceinline__ float bf2f(u16 h) {
  union { u32 u; float f; } v; v.u = ((u32)h) << 16; return v.f;
}
static __device__ __forceinline__ bf16x8 ld_bf8(const u16* p) {
  return __builtin_bit_cast(bf16x8, *(const u16x8*)p);
}
#define MFMA16(a,b,c) __builtin_amdgcn_mfma_f32_16x16x32_bf16((a),(b),(c),0,0,0)

static __device__ __forceinline__ void gload16(const u16* g, u16* lds) {
  __builtin_amdgcn_global_load_lds(
      (const __attribute__((address_space(1))) u32*)g,
      (__attribute__((address_space(3))) u32*)lds, 16, 0, 0);
}

// ============ kA: fused channel-reduce (k partials) + bf16 transpose =======
__global__ __launch_bounds__(256) void kA(
    const float* __restrict__ x, const float* __restrict__ alpha,
    u16* __restrict__ xT, float* __restrict__ kpart) {
  int bid = blockIdx.x;
  int b  = bid >> 5;
  int mt = (bid >> 1) & 15;
  int ch = bid & 1;
  int m0 = mt * 128;
  int tid = threadIdx.x;
  __shared__ float tile[128][25];
  float kacc[12];
  #pragma unroll
  for (int e = 0; e < 12; ++e) kacc[e] = 0.f;

  for (int c = ch*32; c < ch*32 + 32; ++c) {
    const float4* src4 = (const float4*)(x + ((size_t)(b*CC + c)*NN + m0)*TT);
    float a = alpha[c];
    float4 v[3];
    #pragma unroll
    for (int q = 0; q < 3; ++q) v[q] = src4[tid*3 + q];
    __syncthreads();
    #pragma unroll
    for (int q = 0; q < 3; ++q) {
      int idx = tid*3 + q;
      int mm = idx / 6, off = (idx - mm*6)*4;
      tile[mm][off]   = v[q].x; tile[mm][off+1] = v[q].y;
      tile[mm][off+2] = v[q].z; tile[mm][off+3] = v[q].w;
      kacc[q*4+0] += a*v[q].x; kacc[q*4+1] += a*v[q].y;
      kacc[q*4+2] += a*v[q].z; kacc[q*4+3] += a*v[q].w;
    }
    __syncthreads();
    #pragma unroll
    for (int qq = 0; qq < 6; ++qq) {
      int idx = tid*6 + qq;
      int t = idx >> 6, mp = idx & 63;
      u32 lo = f2bf(tile[2*mp][t]);
      u32 hi = f2bf(tile[2*mp+1][t]);
      ((u32*)(xT + ((size_t)((b*CC + c)*TT + t))*NN + m0))[mp] = lo | (hi << 16);
    }
  }
  float* kp = kpart + (size_t)ch*BB*NT + (size_t)b*NT + (size_t)m0*TT + tid*12;
  #pragma unroll
  for (int q = 0; q < 3; ++q)
    *(float4*)(kp + q*4) = make_float4(kacc[q*4], kacc[q*4+1], kacc[q*4+2], kacc[q*4+3]);
}

// ------- K2': kG = k@Gw; emit hi/lo bf16 splits of kG and k (K=32 pad) -----
__global__ __launch_bounds__(256) void k2_prep(
    const float* __restrict__ kpart, const float* __restrict__ Gw,
    u16* __restrict__ kGhi, u16* __restrict__ kGlo,
    u16* __restrict__ kPhi, u16* __restrict__ kPlo) {
  __shared__ float gw[TT*TT];
  for (int i = threadIdx.x; i < TT*TT; i += 256) gw[i] = Gw[i];
  __syncthreads();
  int row = blockIdx.x * blockDim.x + threadIdx.x;
  if (row >= BB*NN) return;
  float kr[TT];
  const float4* s0 = (const float4*)(kpart + (size_t)row*TT);
  const float4* s1 = (const float4*)(kpart + (size_t)BB*NT + (size_t)row*TT);
  #pragma unroll
  for (int q = 0; q < 6; ++q) {
    float4 a = s0[q], bv = s1[q];
    kr[4*q]   = a.x + bv.x; kr[4*q+1] = a.y + bv.y;
    kr[4*q+2] = a.z + bv.z; kr[4*q+3] = a.w + bv.w;
  }
  float o[TT];
  #pragma unroll
  for (int s = 0; s < TT; ++s) o[s] = 0.f;
  #pragma unroll
  for (int t = 0; t < TT; ++t) {
    float kv = kr[t];
    #pragma unroll
    for (int s = 0; s < TT; ++s) o[s] += kv * gw[t*TT + s];
  }
  size_t rb = (size_t)row * 32;
  u32* ghi = (u32*)(kGhi + rb); u32* glo = (u32*)(kGlo + rb);
  u32* phi = (u32*)(kPhi + rb); u32* plo = (u32*)(kPlo + rb);
  #pragma unroll
  for (int sp = 0; sp < 16; ++sp) {
    float v0 = (2*sp   < TT) ? o[2*sp]   : 0.f;
    float v1 = (2*sp+1 < TT) ? o[2*sp+1] : 0.f;
    u16 h0 = f2bf(v0), h1 = f2bf(v1);
    u16 l0 = f2bf(v0 - bf2f(h0)), l1 = f2bf(v1 - bf2f(h1));
    ghi[sp] = (u32)h0 | ((u32)h1 << 16);
    glo[sp] = (u32)l0 | ((u32)l1 << 16);
    float w0 = (2*sp   < TT) ? kr[2*sp]   : 0.f;
    float w1 = (2*sp+1 < TT) ? kr[2*sp+1] : 0.f;
    u16 ph0 = f2bf(w0), ph1 = f2bf(w1);
    u16 pl0 = f2bf(w0 - bf2f(ph0)), pl1 = f2bf(w1 - bf2f(ph1));
    phi[sp] = (u32)ph0 | ((u32)ph1 << 16);
    plo[sp] = (u32)pl0 | ((u32)pl1 << 16);
  }
}

// ---------- kW: W[b,n,m] bf16 = exp(s)*adj ; Zpart[b,n,mt] = sum exp(s) ----
__global__ __launch_bounds__(256) void kW(
    const u16* __restrict__ kGhi, const u16* __restrict__ kGlo,
    const u16* __restrict__ kPhi, const u16* __restrict__ kPlo,
    const float* __restrict__ adj, u16* __restrict__ Wm,
    float* __restrict__ Zpart) {
  int bid = blockIdx.x;
  int b = bid >> 8, nt = (bid >> 4) & 15, mt = bid & 15;
  int tid = threadIdx.x;
  int w = tid >> 6, l = tid & 63;
  __shared__ u16 wlds[128][128];
  size_t kgb = ((size_t)b*NN + nt*128) * 32;
  bf16x8 ahi[2], alo[2];
  #pragma unroll
  for (int nf = 0; nf < 2; ++nf) {
    size_t off = kgb + (size_t)(w*32 + nf*16 + (l & 15))*32 + (l >> 4)*8;
    ahi[nf] = ld_bf8(kGhi + off);
    alo[nf] = ld_bf8(kGlo + off);
  }
  f32x4 acc[2][8];
  #pragma unroll
  for (int mf = 0; mf < 8; ++mf) {
    size_t off = ((size_t)b*NN + mt*128 + mf*16 + (l & 15))*32 + (l >> 4)*8;
    bf16x8 bhi = ld_bf8(kPhi + off);
    bf16x8 blo = ld_bf8(kPlo + off);
    #pragma unroll
    for (int nf = 0; nf < 2; ++nf) {
      f32x4 a = {0.f, 0.f, 0.f, 0.f};
      a = MFMA16(ahi[nf], blo, a);
      a = MFMA16(alo[nf], bhi, a);
      a = MFMA16(ahi[nf], bhi, a);
      acc[nf][mf] = a;
    }
  }
  #pragma unroll
  for (int nf = 0; nf < 2; ++nf)
    #pragma unroll
    for (int r = 0; r < 4; ++r) {
      int nl = w*32 + nf*16 + (l >> 4)*4 + r;
      float rs = 0.f;
      #pragma unroll
      for (int mf = 0; mf < 8; ++mf) {
        int ml = mf*16 + (l & 15);
        float e = __expf(acc[nf][mf][r]);
        rs += e;
        float wv = e * adj[(size_t)(nt*128 + nl)*NN + mt*128 + ml];
        wlds[nl][ml] = f2bf(wv);
      }
      #pragma unroll
      for (int st = 1; st < 16; st <<= 1) rs += __shfl_xor(rs, st);
      if ((l & 15) == 0)
        Zpart[((size_t)b*NN + nt*128 + nl)*16 + mt] = rs;
    }
  __syncthreads();
  int row = tid >> 1, half = tid & 1;
  const u32x4* s4 = (const u32x4*)&wlds[row][half*64];
  u32x4* d4 = (u32x4*)(Wm + ((size_t)(b*NN + nt*128 + row))*NN + mt*128 + half*64);
  #pragma unroll
  for (int q = 0; q < 8; ++q) d4[q] = s4[q];
}

// ---------- k4: out = (W @ X)*rinv — 256x128 tile, BK=32, 2 blocks/CU ------
// First geometry where 2 blocks/CU is register-feasible: 4x2 waves of 64x64
// (acc 64 regs + operands ~32 + addr -> ~120 <= 128 with launch_bounds(512,4));
// LDS 48 KB (A 2x256x32, B 2x128x32) -> two blocks co-resident, cross-block
// overlap soaks the per-step barrier drain (m114 mechanism). Read-traffic/
// BK64-equiv drops 192->128 KB (squarer wave tiles). R9 single-barrier
// ledger: stage kt+1 ungated -> 8 ds_reads -> 4 MFMA clusters gated
// lgkmcnt(3/2/1/0) -> vmcnt(0) -> barrier. Swizzle for 32-u16 rows:
// slot' = l4 ^ ((row>>1)&3), both-sides; uniform 8 lanes/128B-class => ~0
// conflicts (same spread argument as the verified 64-u16 swizzle).
__global__ __launch_bounds__(512, 4) void k4_gemm(
    const u16* __restrict__ Wm, const u16* __restrict__ xT,
    const float* __restrict__ Zpart, float* __restrict__ out) {
  __shared__ __align__(16) u16 sA[2*256*32];   // 32 KB
  __shared__ __align__(16) u16 sB[2*128*32];   // 16 KB
  __shared__ float rinv[256];

  int bid = blockIdx.x;
  int wg = (bid & 7) * 192 + (bid >> 3);       // 1536 = 8*192 bijective
  int b = wg / 96; int rem = wg - b*96;
  int nt = rem / 12, jt = rem - nt*12;         // nt in 0..7, jt in 0..11

  int tid = threadIdx.x;
  int w = tid >> 6, l = tid & 63;
  int wr = w >> 1, wc = w & 1;                 // 4x2 wave grid (64x64 each)
  int l15 = l & 15, l4 = l >> 4;

  // fragment read offset: slot = l4 ^ ((row>>1)&3); row bases = 0 mod 8
  int g = (l4 ^ ((l15 >> 1) & 3)) << 3;        // u16 units
  int rbA = wr*2048 + l15*32;                  // A row = wr*64 + f*16 + l15
  int rbB = wc*2048 + l15*32;                  // B row = wc*64 + cf*16 + l15

  // staging: thread -> (row = tid>>2 [+128 for A's 2nd], slot = tid&3)
  int srow = tid >> 2, sslot = tid & 3;
  int sgx = (sslot ^ ((srow >> 1) & 3)) << 3;  // (srow+128)>>1 ≡ srow>>1 mod 4
  const size_t ROW128 = (size_t)128 * NN;
  const u16* pA = Wm + (size_t)b*NN*NN + (size_t)(nt*256 + srow)*NN + sgx;
  const u16* pB = xT + (size_t)b*JJ*NN + (size_t)(jt*128 + srow)*NN + sgx;
  int wb = w << 9;   // wave-uniform LDS dest (u16); lane adds 16B implicitly

  f32x4 acc[4][4];
  #pragma unroll
  for (int f = 0; f < 4; ++f)
    #pragma unroll
    for (int cf = 0; cf < 4; ++cf) acc[f][cf] = (f32x4){0.f,0.f,0.f,0.f};

  // ---- prologue: rinv from Zpart + stage tile 0 into buf 0, publish ----
  if (tid < 256) {
    const float4* zp = (const float4*)(Zpart + ((size_t)b*NN + nt*256 + tid)*16);
    float4 a = zp[0], bz = zp[1], c = zp[2], d = zp[3];
    float s = a.x+a.y+a.z+a.w + bz.x+bz.y+bz.z+bz.w
            + c.x+c.y+c.z+c.w + d.x+d.y+d.z+d.w;
    rinv[tid] = 1.f / s;
  }
  gload16(pA,          sA + wb);
  gload16(pA + ROW128, sA + 4096 + wb);
  gload16(pB,          sB + wb);
  pA += 32; pB += 32;
  asm volatile("s_waitcnt vmcnt(0)" ::: "memory");
  __builtin_amdgcn_sched_barrier(0);
  __builtin_amdgcn_s_barrier();
  __builtin_amdgcn_sched_barrier(0);

  for (int kt = 0; kt < 64; ++kt) {
    int pbA = (kt & 1) << 13;                  // sA dbuf stride 8192 u16
    int qbA = pbA ^ 8192;
    int pbB = (kt & 1) << 12;                  // sB dbuf stride 4096 u16
    int qbB = pbB ^ 4096;
    // stage kt+1 into the other buffer (ungated; drains at end-of-step)
    if (kt < 63) {
      gload16(pA,          sA + qbA + wb);
      gload16(pA + ROW128, sA + qbA + 4096 + wb);
      gload16(pB,          sB + qbB + wb);
      pA += 32; pB += 32;
    }
    __builtin_amdgcn_sched_barrier(0);

    bf16x8 av[4], bv[4];
    // 8 ds_read_b128: b0..b3 then a0..a3
    #pragma unroll
    for (int cf = 0; cf < 4; ++cf) bv[cf] = ld_bf8(sB + pbB + rbB + cf*512 + g);
    #pragma unroll
    for (int f = 0; f < 4; ++f) av[f] = ld_bf8(sA + pbA + rbA + f*512 + g);

    // cluster f=0: needs b0-3 + a0 (first 5 of 8)
    asm volatile("s_waitcnt lgkmcnt(3)" ::: "memory");
    __builtin_amdgcn_sched_barrier(0);
    __builtin_amdgcn_s_setprio(1);
    #pragma unroll
    for (int cf = 0; cf < 4; ++cf) acc[0][cf] = MFMA16(av[0], bv[cf], acc[0][cf]);
    __builtin_amdgcn_s_setprio(0);
    // cluster f=1 (first 6)
    asm volatile("s_waitcnt lgkmcnt(2)" ::: "memory");
    __builtin_amdgcn_sched_barrier(0);
    __builtin_amdgcn_s_setprio(1);
    #pragma unroll
    for (int cf = 0; cf < 4; ++cf) acc[1][cf] = MFMA16(av[1], bv[cf], acc[1][cf]);
    __builtin_amdgcn_s_setprio(0);
    // cluster f=2 (first 7)
    asm volatile("s_waitcnt lgkmcnt(1)" ::: "memory");
    __builtin_amdgcn_sched_barrier(0);
    __builtin_amdgcn_s_setprio(1);
    #pragma unroll
    for (int cf = 0; cf < 4; ++cf) acc[2][cf] = MFMA16(av[2], bv[cf], acc[2][cf]);
    __builtin_amdgcn_s_setprio(0);
    // cluster f=3 (all 8)
    asm volatile("s_waitcnt lgkmcnt(0)" ::: "memory");
    __builtin_amdgcn_sched_barrier(0);
    __builtin_amdgcn_s_setprio(1);
    #pragma unroll
    for (int cf = 0; cf < 4; ++cf) acc[3][cf] = MFMA16(av[3], bv[cf], acc[3][cf]);
    __builtin_amdgcn_s_setprio(0);

    // end-of-step: drain own gloads (aged a full step), then single barrier
    asm volatile("s_waitcnt vmcnt(0)" ::: "memory");
    __builtin_amdgcn_sched_barrier(0);
    __builtin_amdgcn_s_barrier();
    __builtin_amdgcn_sched_barrier(0);
  }

  // ---- epilogue: normalize + store (rinv in LDS) ----
  int cj[4], tj4[4];
  #pragma unroll
  for (int cf = 0; cf < 4; ++cf) {
    int j = jt*128 + wc*64 + cf*16 + l15;
    cj[cf] = j / TT; tj4[cf] = j - cj[cf]*TT;
  }
  #pragma unroll
  for (int f = 0; f < 4; ++f)
    #pragma unroll
    for (int r = 0; r < 4; ++r) {
      int nl = wr*64 + f*16 + l4*4 + r;
      float rv = rinv[nl];
      #pragma unroll
      for (int cf = 0; cf < 4; ++cf)
        out[((size_t)(b*CC + cj[cf])*NN + nt*256 + nl)*TT + tj4[cf]] = acc[f][cf][r] * rv;
    }
}

extern "C" void kernel_launch(void* const* d_in, const int* in_sizes, int n_in,
                              void* d_out, int out_size, void* d_ws, size_t ws_size,
                              hipStream_t stream) {
  const float* x     = (const float*)d_in[0];
  const float* adj   = (const float*)d_in[1];
  const float* Gw    = (const float*)d_in[2];
  const float* alpha = (const float*)d_in[3];
  float* out = (float*)d_out;

  const size_t XT_B = (size_t)BB*JJ*NN*2;
  const size_t W_B  = (size_t)BB*NN*NN*2;
  const size_t KS_B = (size_t)BB*NN*32*2;
  char* base = (char*)d_ws;
  u16*   xT    = (u16*)base;
  u16*   Wm    = (u16*)(base + XT_B);
  float* kpart = (float*)(base + XT_B);            // overlay on Wm (dead then)
  u16*   kGhi  = (u16*)(base + XT_B + W_B);
  u16*   kGlo  = (u16*)(base + XT_B + W_B + KS_B);
  u16*   kPhi  = (u16*)(base + XT_B + W_B + 2*KS_B);
  u16*   kPlo  = (u16*)(base + XT_B + W_B + 3*KS_B);
  float* Zpart = (float*)(base + XT_B + W_B + 4*KS_B);

  kA<<<512, 256, 0, stream>>>(x, alpha, xT, kpart);
  k2_prep<<<BB*NN/256, 256, 0, stream>>>(kpart, Gw, kGhi, kGlo, kPhi, kPlo);
  kW<<<BB*16*16, 256, 0, stream>>>(kGhi, kGlo, kPhi, kPlo, adj, Wm, Zpart);
  k4_gemm<<<1536, 512, 0, stream>>>(Wm, xT, Zpart, out);
}